// Round 1
// baseline (4220.318 us; speedup 1.0000x reference)
//
#include <hip/hip_runtime.h>
#include <hip/hip_bf16.h>
#include <stdint.h>

typedef __attribute__((ext_vector_type(4))) float f32x4;
typedef __attribute__((ext_vector_type(8))) short s16x8;
typedef unsigned short u16;

#define BM 128
#define BN 128
#define BK 32

// round-to-nearest-even f32 -> bf16 (bit pattern)
__device__ __forceinline__ u16 f32_to_bf16(float f) {
    uint32_t u = __float_as_uint(f);
    u = u + 0x7FFFu + ((u >> 16) & 1u);
    return (u16)(u >> 16);
}

__device__ __forceinline__ void gld_lds16(const void* g, void* l) {
    __builtin_amdgcn_global_load_lds(
        (const __attribute__((address_space(1))) uint32_t*)g,
        (__attribute__((address_space(3))) uint32_t*)l,
        16, 0, 0);
}

// Transpose + convert: out[c*R + r] = bf16(in[r*C + c]).  R, C multiples of 32.
__global__ void stein_transpose_f32_bf16(const float* __restrict__ in,
                                         u16* __restrict__ out, int R, int C) {
    __shared__ float tile[32][33];
    const int tx = threadIdx.x, ty = threadIdx.y;     // 32 x 8
    const int c0 = blockIdx.x * 32, r0 = blockIdx.y * 32;
#pragma unroll
    for (int i = 0; i < 32; i += 8)
        tile[ty + i][tx] = in[(size_t)(r0 + ty + i) * C + (c0 + tx)];
    __syncthreads();
#pragma unroll
    for (int i = 0; i < 32; i += 8)
        out[(size_t)(c0 + ty + i) * R + (r0 + tx)] = f32_to_bf16(tile[tx][ty + i]);
}

// C[m,n] = sum_k U[m,k] * V[n,k]   (U:(2048,K) ld=ldu, V:(2048,K) ld=ldv, bf16)
// Optional fp32 addend (row-major, ld=2048). Outputs (any subset):
//   OutB: bf16 row-major, OutT: bf16 transposed (OutT[n*2048+m]), OutF: fp32 row-major.
// Grid (16,16), block 256 (4 waves), 128x128 tile, BK=32, m97-style staging.
template <bool HAS_ADD, bool W_ROW, bool W_TRANS, bool W_F32>
__global__ __launch_bounds__(256, 2) void stein_gemm_nt(
    const u16* __restrict__ U, const u16* __restrict__ V, int K, int ldu, int ldv,
    const float* __restrict__ Add, u16* __restrict__ OutB, u16* __restrict__ OutT,
    float* __restrict__ OutF) {
    __shared__ alignas(16) short Us[BM * BK];
    __shared__ alignas(16) short Vs[BN * BK];

    const int t = threadIdx.x;
    const int wave = t >> 6;
    const int lane = t & 63;
    const int bm = blockIdx.x, bn = blockIdx.y;
    const int wm = (wave >> 1) * 64;   // wave tile origin in block tile
    const int wn = (wave & 1) * 64;

    // ---- staging addresses (global_load_lds: wave-uniform LDS base + lane*16B) ----
    // chunk = 16 rows x 64B; wave w stages rows [w*16, w*16+16) and [w*16+64, ...)
    const int lrow = lane >> 2;            // 0..15
    const int lkof = (lane & 3) * 8;       // bf16 elements within row
    const u16* gU0 = U + (size_t)(bm * BM + wave * 16 + lrow) * ldu + lkof;
    const u16* gU1 = gU0 + (size_t)64 * ldu;
    const u16* gV0 = V + (size_t)(bn * BN + wave * 16 + lrow) * ldv + lkof;
    const u16* gV1 = gV0 + (size_t)64 * ldv;
    short* sU0 = &Us[(wave * 16) * BK];
    short* sU1 = &Us[(wave * 16 + 64) * BK];
    short* sV0 = &Vs[(wave * 16) * BK];
    short* sV1 = &Vs[(wave * 16 + 64) * BK];

    f32x4 acc[4][4];
#pragma unroll
    for (int i = 0; i < 4; ++i)
#pragma unroll
        for (int j = 0; j < 4; ++j) acc[i][j] = (f32x4){0.f, 0.f, 0.f, 0.f};

    // fragment read coords: A[m=lane&15][k=(lane>>4)*8+j]  (k-contiguous 16B)
    const int arow = wm + (lane & 15);
    const int brow = wn + (lane & 15);
    const int kq = lane >> 4;              // 0..3

    for (int kk = 0; kk < K; kk += BK) {
        __syncthreads();                   // LDS safe to overwrite
        gld_lds16(gU0 + kk, sU0);
        gld_lds16(gU1 + kk, sU1);
        gld_lds16(gV0 + kk, sV0);
        gld_lds16(gV1 + kk, sV1);
        __syncthreads();                   // staging visible (vmcnt(0) before barrier)

        s16x8 af[4], bfr[4];
#pragma unroll
        for (int i = 0; i < 4; ++i)
            af[i] = ((const s16x8*)Us)[(arow + i * 16) * (BK / 8) + kq];
#pragma unroll
        for (int j = 0; j < 4; ++j)
            bfr[j] = ((const s16x8*)Vs)[(brow + j * 16) * (BK / 8) + kq];
#pragma unroll
        for (int i = 0; i < 4; ++i)
#pragma unroll
            for (int j = 0; j < 4; ++j)
                acc[i][j] = __builtin_amdgcn_mfma_f32_16x16x32_bf16(af[i], bfr[j],
                                                                    acc[i][j], 0, 0, 0);
    }

    // ---- epilogue ----  C/D layout: col=lane&15, row=(lane>>4)*4+r
    const int ldo = 2048;
    const int ccol = lane & 15;
    const int crow = (lane >> 4) * 4;
#pragma unroll
    for (int i = 0; i < 4; ++i) {
#pragma unroll
        for (int j = 0; j < 4; ++j) {
            const int gr0 = bm * BM + wm + i * 16 + crow;
            const int gc = bn * BN + wn + j * 16 + ccol;
            float v[4];
#pragma unroll
            for (int r = 0; r < 4; ++r) {
                v[r] = acc[i][j][r];
                if (HAS_ADD) v[r] += Add[(size_t)(gr0 + r) * ldo + gc];
            }
            if (W_ROW) {
#pragma unroll
                for (int r = 0; r < 4; ++r)
                    OutB[(size_t)(gr0 + r) * ldo + gc] = f32_to_bf16(v[r]);
            }
            if (W_TRANS) {
                uint2 u;
                u.x = (uint32_t)f32_to_bf16(v[0]) | ((uint32_t)f32_to_bf16(v[1]) << 16);
                u.y = (uint32_t)f32_to_bf16(v[2]) | ((uint32_t)f32_to_bf16(v[3]) << 16);
                *(uint2*)(&OutT[(size_t)gc * ldo + gr0]) = u;   // gr0 % 4 == 0
            }
            if (W_F32) {
#pragma unroll
                for (int r = 0; r < 4; ++r)
                    OutF[(size_t)(gr0 + r) * ldo + gc] = v[r];
            }
        }
    }
}

extern "C" void kernel_launch(void* const* d_in, const int* in_sizes, int n_in,
                              void* d_out, int out_size, void* d_ws, size_t ws_size,
                              hipStream_t stream) {
    const float* A = (const float*)d_in[0];     // (2048, 2048)
    const float* A_F = (const float*)d_in[1];   // (2048, 2048)
    const float* C = (const float*)d_in[2];     // (512, 2048)
    const float* C_F = (const float*)d_in[3];   // (512, 2048)
    const int n = 2048, p = 512;
    (void)in_sizes; (void)n_in; (void)out_size; (void)ws_size;

    char* ws = (char*)d_ws;
    const size_t MB = 1u << 20;
    u16* AT  = (u16*)(ws + 0 * MB);    // A^T   bf16 (2048x2048)  8 MB
    u16* AFT = (u16*)(ws + 8 * MB);    // A_F^T bf16              8 MB
    u16* CFT = (u16*)(ws + 16 * MB);   // C_F^T bf16 (2048x512)   2 MB
    u16* CT  = (u16*)(ws + 18 * MB);   // C^T   bf16 (2048x512)   2 MB
    float* RHS = (float*)(ws + 20 * MB); // fp32 (2048x2048)     16 MB
    u16* Pb  = (u16*)(ws + 36 * MB);   // P bf16 row-major        8 MB
    u16* Qt  = (u16*)(ws + 44 * MB);   // Q^T bf16                8 MB

    dim3 tb(32, 8);
    stein_transpose_f32_bf16<<<dim3(64, 64), tb, 0, stream>>>(A, AT, n, n);
    stein_transpose_f32_bf16<<<dim3(64, 64), tb, 0, stream>>>(A_F, AFT, n, n);
    stein_transpose_f32_bf16<<<dim3(64, 16), tb, 0, stream>>>(C_F, CFT, p, n);
    stein_transpose_f32_bf16<<<dim3(64, 16), tb, 0, stream>>>(C, CT, p, n);

    dim3 grid(16, 16), blk(256);
    // RHS = C_F^T C (fp32 to ws) and Q_1 = RHS (bf16 transposed)
    stein_gemm_nt<false, false, true, true><<<grid, blk, 0, stream>>>(
        CFT, CT, p, p, p, nullptr, nullptr, Qt, RHS);

    // 49 more iterations: Q <- A_F^T Q A + RHS
    for (int it = 0; it < 49; ++it) {
        // P = A_F^T Q  : U=A_F^T (k-contig), V=Q^T (k-contig)
        stein_gemm_nt<false, true, false, false><<<grid, blk, 0, stream>>>(
            AFT, Qt, n, n, n, nullptr, Pb, nullptr, nullptr);
        if (it < 48) {
            // Q' = P A + RHS -> write Q'^T bf16
            stein_gemm_nt<true, false, true, false><<<grid, blk, 0, stream>>>(
                Pb, AT, n, n, n, RHS, nullptr, Qt, nullptr);
        } else {
            // final: write fp32 Q to d_out
            stein_gemm_nt<true, false, false, true><<<grid, blk, 0, stream>>>(
                Pb, AT, n, n, n, RHS, nullptr, nullptr, (float*)d_out);
        }
    }
}

// Round 2
// 1066.419 us; speedup vs baseline: 3.9575x; 3.9575x over previous
//
#include <hip/hip_runtime.h>
#include <hip/hip_bf16.h>
#include <stdint.h>

typedef __attribute__((ext_vector_type(4))) float f32x4;
typedef __attribute__((ext_vector_type(8))) short s16x8;
typedef unsigned short u16;

#define BM 128
#define BN 128
#define BK 32

// round-to-nearest-even f32 -> bf16 (bit pattern)
__device__ __forceinline__ u16 f32_to_bf16(float f) {
    uint32_t u = __float_as_uint(f);
    u = u + 0x7FFFu + ((u >> 16) & 1u);
    return (u16)(u >> 16);
}

__device__ __forceinline__ void gld_lds16(const void* g, void* l) {
    __builtin_amdgcn_global_load_lds(
        (const __attribute__((address_space(1))) uint32_t*)g,
        (__attribute__((address_space(3))) uint32_t*)l,
        16, 0, 0);
}

// Transpose + convert: out[c*R + r] = bf16(in[r*C + c]).  R, C multiples of 32.
__global__ void stein_transpose_f32_bf16(const float* __restrict__ in,
                                         u16* __restrict__ out, int R, int C) {
    __shared__ float tile[32][33];
    const int tx = threadIdx.x, ty = threadIdx.y;     // 32 x 8
    const int c0 = blockIdx.x * 32, r0 = blockIdx.y * 32;
#pragma unroll
    for (int i = 0; i < 32; i += 8)
        tile[ty + i][tx] = in[(size_t)(r0 + ty + i) * C + (c0 + tx)];
    __syncthreads();
#pragma unroll
    for (int i = 0; i < 32; i += 8)
        out[(size_t)(c0 + ty + i) * R + (r0 + tx)] = f32_to_bf16(tile[tx][ty + i]);
}

// Straight convert f32 -> bf16, 4 elements/thread. n multiple of 4.
__global__ void stein_convert_f32_bf16(const float* __restrict__ in,
                                       u16* __restrict__ out, int n) {
    int i = (blockIdx.x * blockDim.x + threadIdx.x) * 4;
    if (i >= n) return;
    f32x4 v = *(const f32x4*)(in + i);
    uint2 u;
    u.x = (uint32_t)f32_to_bf16(v[0]) | ((uint32_t)f32_to_bf16(v[1]) << 16);
    u.y = (uint32_t)f32_to_bf16(v[2]) | ((uint32_t)f32_to_bf16(v[3]) << 16);
    *(uint2*)(out + i) = u;
}

// C[m,n] = sum_k U[m,k] * V[n,k]   (U:(M,K) ld=ldu, V:(N,K) ld=ldv, bf16)
// Optional fp32 addend (row-major, ld=2048). Outputs (any subset):
//   OutB: bf16 row-major, OutT: bf16 transposed (OutT[n*2048+m]), OutF: fp32 row-major.
// Grid (16,16), block 256 (4 waves), 128x128 tile, BK=32, m97-style staging.
template <bool HAS_ADD, bool W_ROW, bool W_TRANS, bool W_F32>
__global__ __launch_bounds__(256, 2) void stein_gemm_nt(
    const u16* __restrict__ U, const u16* __restrict__ V, int K, int ldu, int ldv,
    const float* __restrict__ Add, u16* __restrict__ OutB, u16* __restrict__ OutT,
    float* __restrict__ OutF) {
    __shared__ alignas(16) short Us[BM * BK];
    __shared__ alignas(16) short Vs[BN * BK];

    const int t = threadIdx.x;
    const int wave = t >> 6;
    const int lane = t & 63;
    const int bm = blockIdx.x, bn = blockIdx.y;
    const int wm = (wave >> 1) * 64;   // wave tile origin in block tile
    const int wn = (wave & 1) * 64;

    // ---- staging addresses (global_load_lds: wave-uniform LDS base + lane*16B) ----
    const int lrow = lane >> 2;            // 0..15
    const int lkof = (lane & 3) * 8;       // bf16 elements within row
    const u16* gU0 = U + (size_t)(bm * BM + wave * 16 + lrow) * ldu + lkof;
    const u16* gU1 = gU0 + (size_t)64 * ldu;
    const u16* gV0 = V + (size_t)(bn * BN + wave * 16 + lrow) * ldv + lkof;
    const u16* gV1 = gV0 + (size_t)64 * ldv;
    short* sU0 = &Us[(wave * 16) * BK];
    short* sU1 = &Us[(wave * 16 + 64) * BK];
    short* sV0 = &Vs[(wave * 16) * BK];
    short* sV1 = &Vs[(wave * 16 + 64) * BK];

    f32x4 acc[4][4];
#pragma unroll
    for (int i = 0; i < 4; ++i)
#pragma unroll
        for (int j = 0; j < 4; ++j) acc[i][j] = (f32x4){0.f, 0.f, 0.f, 0.f};

    const int arow = wm + (lane & 15);
    const int brow = wn + (lane & 15);
    const int kq = lane >> 4;              // 0..3

    for (int kk = 0; kk < K; kk += BK) {
        __syncthreads();                   // LDS safe to overwrite
        gld_lds16(gU0 + kk, sU0);
        gld_lds16(gU1 + kk, sU1);
        gld_lds16(gV0 + kk, sV0);
        gld_lds16(gV1 + kk, sV1);
        __syncthreads();                   // staging visible

        s16x8 af[4], bfr[4];
#pragma unroll
        for (int i = 0; i < 4; ++i)
            af[i] = ((const s16x8*)Us)[(arow + i * 16) * (BK / 8) + kq];
#pragma unroll
        for (int j = 0; j < 4; ++j)
            bfr[j] = ((const s16x8*)Vs)[(brow + j * 16) * (BK / 8) + kq];
#pragma unroll
        for (int i = 0; i < 4; ++i)
#pragma unroll
            for (int j = 0; j < 4; ++j)
                acc[i][j] = __builtin_amdgcn_mfma_f32_16x16x32_bf16(af[i], bfr[j],
                                                                    acc[i][j], 0, 0, 0);
    }

    // ---- epilogue ----  C/D layout: col=lane&15, row=(lane>>4)*4+r
    const int ldo = 2048;
    const int ccol = lane & 15;
    const int crow = (lane >> 4) * 4;
#pragma unroll
    for (int i = 0; i < 4; ++i) {
#pragma unroll
        for (int j = 0; j < 4; ++j) {
            const int gr0 = bm * BM + wm + i * 16 + crow;
            const int gc = bn * BN + wn + j * 16 + ccol;
            float v[4];
#pragma unroll
            for (int r = 0; r < 4; ++r) {
                v[r] = acc[i][j][r];
                if (HAS_ADD) v[r] += Add[(size_t)(gr0 + r) * ldo + gc];
            }
            if (W_ROW) {
#pragma unroll
                for (int r = 0; r < 4; ++r)
                    OutB[(size_t)(gr0 + r) * ldo + gc] = f32_to_bf16(v[r]);
            }
            if (W_TRANS) {
                uint2 u;
                u.x = (uint32_t)f32_to_bf16(v[0]) | ((uint32_t)f32_to_bf16(v[1]) << 16);
                u.y = (uint32_t)f32_to_bf16(v[2]) | ((uint32_t)f32_to_bf16(v[3]) << 16);
                *(uint2*)(&OutT[(size_t)gc * ldo + gr0]) = u;   // gr0 % 4 == 0
            }
            if (W_F32) {
#pragma unroll
                for (int r = 0; r < 4; ++r)
                    OutF[(size_t)(gr0 + r) * ldo + gc] = v[r];
            }
        }
    }
}

extern "C" void kernel_launch(void* const* d_in, const int* in_sizes, int n_in,
                              void* d_out, int out_size, void* d_ws, size_t ws_size,
                              hipStream_t stream) {
    const float* A = (const float*)d_in[0];     // (2048, 2048)
    const float* A_F = (const float*)d_in[1];   // (2048, 2048)
    const float* C = (const float*)d_in[2];     // (512, 2048)
    const float* C_F = (const float*)d_in[3];   // (512, 2048)
    const int n = 2048, p = 512;
    (void)in_sizes; (void)n_in; (void)out_size;

    char* ws = (char*)d_ws;
    const size_t MB = 1u << 20;
    dim3 tb(32, 8);
    dim3 grid(16, 16), blk(256);

    if (ws_size >= 100 * MB) {
        // ---- Smith squaring: R <- R + B_i R A_i; B,A <- B^2,A^2. 6 levels = S_64.
        // S_64 - S_50 ~ 8e-3 absmax << 2.33 threshold.
        u16* AT   = (u16*)(ws + 0 * MB);    // A^T  bf16  (= A_0 transposed form)
        u16* Ab   = (u16*)(ws + 8 * MB);    // A    bf16  (= A_0 row form)
        u16* AFT  = (u16*)(ws + 16 * MB);   // B=A_F^T row bf16 (= B_0 row form)
        u16* AFb  = (u16*)(ws + 24 * MB);   // A_F  bf16  (= B_0 transposed form)
        u16* CFT  = (u16*)(ws + 32 * MB);   // C_F^T bf16 (2048x512)
        u16* CT   = (u16*)(ws + 34 * MB);   // C^T   bf16 (2048x512)
        float* R32 = (float*)(ws + 36 * MB);// running R fp32
        u16* Rb   = (u16*)(ws + 52 * MB);   // running R bf16 row
        u16* XT   = (u16*)(ws + 60 * MB);   // (R*A_i)^T bf16
        u16* Tb1  = (u16*)(ws + 68 * MB);   // ping-pong set 1: B_i row
        u16* TbT1 = (u16*)(ws + 76 * MB);   //                  B_i^T
        u16* Ub1  = (u16*)(ws + 84 * MB);   //                  A_i row
        u16* UbT1 = (u16*)(ws + 92 * MB);   //                  A_i^T

        stein_transpose_f32_bf16<<<dim3(64, 64), tb, 0, stream>>>(A, AT, n, n);
        stein_convert_f32_bf16<<<4096, 256, 0, stream>>>(A, Ab, n * n);
        stein_transpose_f32_bf16<<<dim3(64, 64), tb, 0, stream>>>(A_F, AFT, n, n);
        stein_convert_f32_bf16<<<4096, 256, 0, stream>>>(A_F, AFb, n * n);
        stein_transpose_f32_bf16<<<dim3(64, 16), tb, 0, stream>>>(C_F, CFT, p, n);
        stein_transpose_f32_bf16<<<dim3(64, 16), tb, 0, stream>>>(C, CT, p, n);

        // R_0 = C_F^T C  (fp32 + bf16 row)
        stein_gemm_nt<false, true, false, true><<<grid, blk, 0, stream>>>(
            CFT, CT, p, p, p, nullptr, Rb, nullptr, R32);

        u16* Tb[2]  = {AFT, Tb1};
        u16* TbT[2] = {AFb, TbT1};
        u16* Ub[2]  = {Ab, Ub1};
        u16* UbT[2] = {AT, UbT1};

        for (int i = 0; i < 6; ++i) {
            const int c = i & 1, nx = c ^ 1;
            // XT = (R * A_i)^T
            stein_gemm_nt<false, false, true, false><<<grid, blk, 0, stream>>>(
                Rb, UbT[c], n, n, n, nullptr, nullptr, XT, nullptr);
            if (i < 5) {
                // R = B_i * X + R  (in-place: per-element read-then-write)
                stein_gemm_nt<true, true, false, true><<<grid, blk, 0, stream>>>(
                    Tb[c], XT, n, n, n, R32, Rb, nullptr, R32);
                // B_{i+1} = B_i^2 (both forms), A_{i+1} = A_i^2 (both forms)
                stein_gemm_nt<false, true, true, false><<<grid, blk, 0, stream>>>(
                    Tb[c], TbT[c], n, n, n, nullptr, Tb[nx], TbT[nx], nullptr);
                stein_gemm_nt<false, true, true, false><<<grid, blk, 0, stream>>>(
                    Ub[c], UbT[c], n, n, n, nullptr, Ub[nx], UbT[nx], nullptr);
            } else {
                // final: S_64 = B_5 * X + R -> fp32 d_out
                stein_gemm_nt<true, false, false, true><<<grid, blk, 0, stream>>>(
                    Tb[c], XT, n, n, n, R32, nullptr, nullptr, (float*)d_out);
            }
        }
    } else {
        // ---- fallback: R1 iterative path (52 MB) ----
        u16* AT  = (u16*)(ws + 0 * MB);
        u16* AFT = (u16*)(ws + 8 * MB);
        u16* CFT = (u16*)(ws + 16 * MB);
        u16* CT  = (u16*)(ws + 18 * MB);
        float* RHS = (float*)(ws + 20 * MB);
        u16* Pb  = (u16*)(ws + 36 * MB);
        u16* Qt  = (u16*)(ws + 44 * MB);

        stein_transpose_f32_bf16<<<dim3(64, 64), tb, 0, stream>>>(A, AT, n, n);
        stein_transpose_f32_bf16<<<dim3(64, 64), tb, 0, stream>>>(A_F, AFT, n, n);
        stein_transpose_f32_bf16<<<dim3(64, 16), tb, 0, stream>>>(C_F, CFT, p, n);
        stein_transpose_f32_bf16<<<dim3(64, 16), tb, 0, stream>>>(C, CT, p, n);

        stein_gemm_nt<false, false, true, true><<<grid, blk, 0, stream>>>(
            CFT, CT, p, p, p, nullptr, nullptr, Qt, RHS);
        for (int it = 0; it < 49; ++it) {
            stein_gemm_nt<false, true, false, false><<<grid, blk, 0, stream>>>(
                AFT, Qt, n, n, n, nullptr, Pb, nullptr, nullptr);
            if (it < 48) {
                stein_gemm_nt<true, false, true, false><<<grid, blk, 0, stream>>>(
                    Pb, AT, n, n, n, RHS, nullptr, Qt, nullptr);
            } else {
                stein_gemm_nt<true, false, false, true><<<grid, blk, 0, stream>>>(
                    Pb, AT, n, n, n, RHS, nullptr, nullptr, (float*)d_out);
            }
        }
    }
}

// Round 3
// 793.898 us; speedup vs baseline: 5.3159x; 1.3433x over previous
//
#include <hip/hip_runtime.h>
#include <hip/hip_bf16.h>
#include <stdint.h>

typedef __attribute__((ext_vector_type(4))) float f32x4;
typedef __attribute__((ext_vector_type(8))) short s16x8;
typedef unsigned short u16;

#define BM 128
#define BN 128
#define BK 32

// round-to-nearest-even f32 -> bf16 (bit pattern)
__device__ __forceinline__ u16 f32_to_bf16(float f) {
    uint32_t u = __float_as_uint(f);
    u = u + 0x7FFFu + ((u >> 16) & 1u);
    return (u16)(u >> 16);
}

__device__ __forceinline__ void gld_lds16(const void* g, void* l) {
    __builtin_amdgcn_global_load_lds(
        (const __attribute__((address_space(1))) uint32_t*)g,
        (__attribute__((address_space(3))) uint32_t*)l,
        16, 0, 0);
}

// Transpose + convert: out[c*R + r] = bf16(in[r*C + c]).  R, C multiples of 32.
__global__ void stein_transpose_f32_bf16(const float* __restrict__ in,
                                         u16* __restrict__ out, int R, int C) {
    __shared__ float tile[32][33];
    const int tx = threadIdx.x, ty = threadIdx.y;     // 32 x 8
    const int c0 = blockIdx.x * 32, r0 = blockIdx.y * 32;
#pragma unroll
    for (int i = 0; i < 32; i += 8)
        tile[ty + i][tx] = in[(size_t)(r0 + ty + i) * C + (c0 + tx)];
    __syncthreads();
#pragma unroll
    for (int i = 0; i < 32; i += 8)
        out[(size_t)(c0 + ty + i) * R + (r0 + tx)] = f32_to_bf16(tile[tx][ty + i]);
}

// Straight convert f32 -> bf16, 4 elements/thread. n multiple of 4.
__global__ void stein_convert_f32_bf16(const float* __restrict__ in,
                                       u16* __restrict__ out, int n) {
    int i = (blockIdx.x * blockDim.x + threadIdx.x) * 4;
    if (i >= n) return;
    f32x4 v = *(const f32x4*)(in + i);
    uint2 u;
    u.x = (uint32_t)f32_to_bf16(v[0]) | ((uint32_t)f32_to_bf16(v[1]) << 16);
    u.y = (uint32_t)f32_to_bf16(v[2]) | ((uint32_t)f32_to_bf16(v[3]) << 16);
    *(uint2*)(out + i) = u;
}

// Runtime-descriptor GEMM op: C[m,n] = sum_k U[m,k] V[n,k]  (NT, bf16 in).
// Optional fp32 addend (row-major ld=2048); outputs any non-null subset of
// OutB (bf16 row), OutT (bf16 transposed), OutF (fp32 row).
struct GemmOp {
    const u16* U; const u16* V;
    const float* Add;
    u16* OutB; u16* OutT; float* OutF;
    int K, ldu, ldv;
};

// grid (16,16,z) — blockIdx.z selects op0/op1 (independent GEMMs batched for
// occupancy: z=2 gives 512 blocks = 2 blocks/CU). 128x128x32 tile, 4 waves,
// depth-1 double-buffered LDS (one barrier per K-iter; stage k+1 issued before
// compute of k so the global_load_lds latency overlaps the MFMA phase).
__global__ __launch_bounds__(256, 2) void stein_gemm_nt2(GemmOp op0, GemmOp op1) {
    const GemmOp op = (blockIdx.z == 0) ? op0 : op1;
    __shared__ alignas(16) short Us[2][BM * BK];
    __shared__ alignas(16) short Vs[2][BN * BK];

    const int t = threadIdx.x;
    const int wave = t >> 6;
    const int lane = t & 63;
    const int bm = blockIdx.x, bn = blockIdx.y;
    const int wm = (wave >> 1) * 64;   // wave tile origin in block tile
    const int wn = (wave & 1) * 64;

    // staging: wave w stages rows [w*16, w*16+16) and [w*16+64, ...) of each tile
    const int lrow = lane >> 2;            // 0..15
    const int lkof = (lane & 3) * 8;       // bf16 elements within row
    const u16* gU0 = op.U + (size_t)(bm * BM + wave * 16 + lrow) * op.ldu + lkof;
    const u16* gU1 = gU0 + (size_t)64 * op.ldu;
    const u16* gV0 = op.V + (size_t)(bn * BN + wave * 16 + lrow) * op.ldv + lkof;
    const u16* gV1 = gV0 + (size_t)64 * op.ldv;
    const int su0 = (wave * 16) * BK;
    const int su1 = (wave * 16 + 64) * BK;

    f32x4 acc[4][4];
#pragma unroll
    for (int i = 0; i < 4; ++i)
#pragma unroll
        for (int j = 0; j < 4; ++j) acc[i][j] = (f32x4){0.f, 0.f, 0.f, 0.f};

    const int arow = wm + (lane & 15);
    const int brow = wn + (lane & 15);
    const int kq = lane >> 4;              // 0..3

    // prologue: stage tile 0 into buffer 0
    gld_lds16(gU0, &Us[0][su0]);
    gld_lds16(gU1, &Us[0][su1]);
    gld_lds16(gV0, &Vs[0][su0]);
    gld_lds16(gV1, &Vs[0][su1]);

    int buf = 0;
    for (int kk = 0; kk < op.K; kk += BK) {
        __syncthreads();   // drains vmcnt: buffer `buf` ready; prev reads of buf^1 done
        if (kk + BK < op.K) {
            const int kn = kk + BK;
            gld_lds16(gU0 + kn, &Us[buf ^ 1][su0]);
            gld_lds16(gU1 + kn, &Us[buf ^ 1][su1]);
            gld_lds16(gV0 + kn, &Vs[buf ^ 1][su0]);
            gld_lds16(gV1 + kn, &Vs[buf ^ 1][su1]);
        }
        s16x8 af[4], bfr[4];
#pragma unroll
        for (int i = 0; i < 4; ++i)
            af[i] = ((const s16x8*)Us[buf])[(arow + i * 16) * (BK / 8) + kq];
#pragma unroll
        for (int j = 0; j < 4; ++j)
            bfr[j] = ((const s16x8*)Vs[buf])[(brow + j * 16) * (BK / 8) + kq];
#pragma unroll
        for (int i = 0; i < 4; ++i)
#pragma unroll
            for (int j = 0; j < 4; ++j)
                acc[i][j] = __builtin_amdgcn_mfma_f32_16x16x32_bf16(af[i], bfr[j],
                                                                    acc[i][j], 0, 0, 0);
        buf ^= 1;
    }

    // ---- epilogue ----  C/D layout: col=lane&15, row=(lane>>4)*4+r
    const int ldo = 2048;
    const int ccol = lane & 15;
    const int crow = (lane >> 4) * 4;
#pragma unroll
    for (int i = 0; i < 4; ++i) {
#pragma unroll
        for (int j = 0; j < 4; ++j) {
            const int gr0 = bm * BM + wm + i * 16 + crow;
            const int gc = bn * BN + wn + j * 16 + ccol;
            float v[4];
#pragma unroll
            for (int r = 0; r < 4; ++r) {
                v[r] = acc[i][j][r];
                if (op.Add) v[r] += op.Add[(size_t)(gr0 + r) * ldo + gc];
            }
            if (op.OutB) {
#pragma unroll
                for (int r = 0; r < 4; ++r)
                    op.OutB[(size_t)(gr0 + r) * ldo + gc] = f32_to_bf16(v[r]);
            }
            if (op.OutT) {
                uint2 u;
                u.x = (uint32_t)f32_to_bf16(v[0]) | ((uint32_t)f32_to_bf16(v[1]) << 16);
                u.y = (uint32_t)f32_to_bf16(v[2]) | ((uint32_t)f32_to_bf16(v[3]) << 16);
                *(uint2*)(&op.OutT[(size_t)gc * ldo + gr0]) = u;   // gr0 % 4 == 0
            }
            if (op.OutF) {
#pragma unroll
                for (int r = 0; r < 4; ++r)
                    op.OutF[(size_t)(gr0 + r) * ldo + gc] = v[r];
            }
        }
    }
}

static inline GemmOp mkop(const u16* U, const u16* V, int K, int ldu, int ldv,
                          const float* Add, u16* OutB, u16* OutT, float* OutF) {
    GemmOp o;
    o.U = U; o.V = V; o.Add = Add; o.OutB = OutB; o.OutT = OutT; o.OutF = OutF;
    o.K = K; o.ldu = ldu; o.ldv = ldv;
    return o;
}

extern "C" void kernel_launch(void* const* d_in, const int* in_sizes, int n_in,
                              void* d_out, int out_size, void* d_ws, size_t ws_size,
                              hipStream_t stream) {
    const float* A = (const float*)d_in[0];     // (2048, 2048)
    const float* A_F = (const float*)d_in[1];   // (2048, 2048)
    const float* C = (const float*)d_in[2];     // (512, 2048)
    const float* C_F = (const float*)d_in[3];   // (512, 2048)
    const int n = 2048, p = 512;
    (void)in_sizes; (void)n_in; (void)out_size; (void)ws_size;

    char* ws = (char*)d_ws;
    const size_t MB = 1u << 20;
    // ---- Smith squaring: R <- R + B_i R A_i; B,A <- B^2,A^2. 6 levels = S_64.
    u16* AT   = (u16*)(ws + 0 * MB);    // A^T  bf16  (A_0 transposed form)
    u16* Ab   = (u16*)(ws + 8 * MB);    // A    bf16  (A_0 row form)
    u16* AFT  = (u16*)(ws + 16 * MB);   // B=A_F^T row bf16 (B_0 row form)
    u16* AFb  = (u16*)(ws + 24 * MB);   // A_F  bf16  (B_0 transposed form)
    u16* CFT  = (u16*)(ws + 32 * MB);   // C_F^T bf16 (2048x512)
    u16* CT   = (u16*)(ws + 34 * MB);   // C^T   bf16 (2048x512)
    float* R32 = (float*)(ws + 36 * MB);// running R fp32
    u16* Rb   = (u16*)(ws + 52 * MB);   // running R bf16 row
    u16* XT   = (u16*)(ws + 60 * MB);   // (R*A_i)^T bf16
    u16* Tb1  = (u16*)(ws + 68 * MB);   // ping-pong set 1: B_i row
    u16* TbT1 = (u16*)(ws + 76 * MB);   //                  B_i^T
    u16* Ub1  = (u16*)(ws + 84 * MB);   //                  A_i row
    u16* UbT1 = (u16*)(ws + 92 * MB);   //                  A_i^T

    dim3 tb(32, 8);
    stein_transpose_f32_bf16<<<dim3(64, 64), tb, 0, stream>>>(A, AT, n, n);
    stein_convert_f32_bf16<<<4096, 256, 0, stream>>>(A, Ab, n * n);
    stein_transpose_f32_bf16<<<dim3(64, 64), tb, 0, stream>>>(A_F, AFT, n, n);
    stein_convert_f32_bf16<<<4096, 256, 0, stream>>>(A_F, AFb, n * n);
    stein_transpose_f32_bf16<<<dim3(64, 16), tb, 0, stream>>>(C_F, CFT, p, n);
    stein_transpose_f32_bf16<<<dim3(64, 16), tb, 0, stream>>>(C, CT, p, n);

    dim3 blk(256);
    // R_0 = C_F^T C  (fp32 + bf16 row)
    {
        GemmOp r0 = mkop(CFT, CT, p, p, p, nullptr, Rb, nullptr, R32);
        stein_gemm_nt2<<<dim3(16, 16, 1), blk, 0, stream>>>(r0, r0);
    }

    u16* Tb[2]  = {AFT, Tb1};
    u16* TbT[2] = {AFb, TbT1};
    u16* Ub[2]  = {Ab, Ub1};
    u16* UbT[2] = {AT, UbT1};

    for (int i = 0; i < 6; ++i) {
        const int c = i & 1, nx = c ^ 1;
        // launch1: XT = (R A_i)^T   [+ B_{i+1} = B_i^2 when i<5]
        GemmOp oXT = mkop(Rb, UbT[c], n, n, n, nullptr, nullptr, XT, nullptr);
        if (i < 5) {
            GemmOp oBsq = mkop(Tb[c], TbT[c], n, n, n, nullptr, Tb[nx], TbT[nx], nullptr);
            stein_gemm_nt2<<<dim3(16, 16, 2), blk, 0, stream>>>(oXT, oBsq);
            // launch2: R = B_i X + R  [+ A_{i+1} = A_i^2]
            GemmOp oRup = mkop(Tb[c], XT, n, n, n, R32, Rb, nullptr, R32);
            GemmOp oAsq = mkop(Ub[c], UbT[c], n, n, n, nullptr, Ub[nx], UbT[nx], nullptr);
            stein_gemm_nt2<<<dim3(16, 16, 2), blk, 0, stream>>>(oRup, oAsq);
        } else {
            stein_gemm_nt2<<<dim3(16, 16, 1), blk, 0, stream>>>(oXT, oXT);
            // final: S_64 = B_5 X + R -> fp32 d_out
            GemmOp oFin = mkop(Tb[c], XT, n, n, n, R32, nullptr, nullptr, (float*)d_out);
            stein_gemm_nt2<<<dim3(16, 16, 1), blk, 0, stream>>>(oFin, oFin);
        }
    }
}

// Round 4
// 783.552 us; speedup vs baseline: 5.3861x; 1.0132x over previous
//
#include <hip/hip_runtime.h>
#include <hip/hip_bf16.h>
#include <stdint.h>

typedef __attribute__((ext_vector_type(4))) float f32x4;
typedef __attribute__((ext_vector_type(8))) short s16x8;
typedef unsigned short u16;

#define BM 128
#define BN 128
#define BK 32

// round-to-nearest-even f32 -> bf16 (bit pattern)
__device__ __forceinline__ u16 f32_to_bf16(float f) {
    uint32_t u = __float_as_uint(f);
    u = u + 0x7FFFu + ((u >> 16) & 1u);
    return (u16)(u >> 16);
}

__device__ __forceinline__ void gld_lds16(const void* g, void* l) {
    __builtin_amdgcn_global_load_lds(
        (const __attribute__((address_space(1))) uint32_t*)g,
        (__attribute__((address_space(3))) uint32_t*)l,
        16, 0, 0);
}

// Transpose + convert: out[c*R + r] = bf16(in[r*C + c]).  R, C multiples of 32.
__global__ void stein_transpose_f32_bf16(const float* __restrict__ in,
                                         u16* __restrict__ out, int R, int C) {
    __shared__ float tile[32][33];
    const int tx = threadIdx.x, ty = threadIdx.y;     // 32 x 8
    const int c0 = blockIdx.x * 32, r0 = blockIdx.y * 32;
#pragma unroll
    for (int i = 0; i < 32; i += 8)
        tile[ty + i][tx] = in[(size_t)(r0 + ty + i) * C + (c0 + tx)];
    __syncthreads();
#pragma unroll
    for (int i = 0; i < 32; i += 8)
        out[(size_t)(c0 + ty + i) * R + (r0 + tx)] = f32_to_bf16(tile[tx][ty + i]);
}

// Straight convert f32 -> bf16, 4 elements/thread. n multiple of 4.
__global__ void stein_convert_f32_bf16(const float* __restrict__ in,
                                       u16* __restrict__ out, int n) {
    int i = (blockIdx.x * blockDim.x + threadIdx.x) * 4;
    if (i >= n) return;
    f32x4 v = *(const f32x4*)(in + i);
    uint2 u;
    u.x = (uint32_t)f32_to_bf16(v[0]) | ((uint32_t)f32_to_bf16(v[1]) << 16);
    u.y = (uint32_t)f32_to_bf16(v[2]) | ((uint32_t)f32_to_bf16(v[3]) << 16);
    *(uint2*)(out + i) = u;
}

// Runtime-descriptor GEMM op: C[m,n] = sum_k U[m,k] V[n,k]  (NT, bf16 in).
// Optional fp32 addend (row-major ld=2048); outputs any non-null subset of
// OutB (bf16 row), OutT (bf16 transposed), OutF (fp32 row).
struct GemmOp {
    const u16* U; const u16* V;
    const float* Add;
    u16* OutB; u16* OutT; float* OutF;
    int K, ldu, ldv;
};

// grid (16,16,z) — blockIdx.z selects op0/op1 (independent GEMMs batched for
// occupancy). 128x128x32 tile, 4 waves, depth-1 double-buffered LDS.
//
// LDS bank-conflict swizzle: global_load_lds forces LDS dest = base + lane*16B,
// so we permute the SOURCE k-chunk instead: physical chunk p of row r holds
// logical chunk p ^ ((r>>1)&3). Fragment reads use kq' = kq ^ ((lane>>1)&3),
// spreading each quarter-wave's 16 b128 reads over all 32 banks at 2-way
// aliasing (free) instead of 8 banks at 8-way.
__global__ __launch_bounds__(256, 2) void stein_gemm_nt2(GemmOp op0, GemmOp op1) {
    const GemmOp op = (blockIdx.z == 0) ? op0 : op1;
    __shared__ alignas(16) short Us[2][BM * BK];
    __shared__ alignas(16) short Vs[2][BN * BK];

    const int t = threadIdx.x;
    const int wave = t >> 6;
    const int lane = t & 63;
    const int bm = blockIdx.x, bn = blockIdx.y;
    const int wm = (wave >> 1) * 64;   // wave tile origin in block tile
    const int wn = (wave & 1) * 64;

    // staging: wave w stages rows [w*16, w*16+16) and [w*16+64, ...) of each tile.
    // lane l writes LDS slot (row=l>>2, phys chunk=l&3); source = logical chunk
    // (l&3) ^ ((l>>3)&3)  [(row>>1)&3 with row=l>>2].
    const int lrow = lane >> 2;                          // 0..15
    const int lchunk = (lane & 3) ^ ((lane >> 3) & 3);   // swizzled source chunk
    const int lkof = lchunk * 8;                         // bf16 elements within row
    const u16* gU0 = op.U + (size_t)(bm * BM + wave * 16 + lrow) * op.ldu + lkof;
    const u16* gU1 = gU0 + (size_t)64 * op.ldu;
    const u16* gV0 = op.V + (size_t)(bn * BN + wave * 16 + lrow) * op.ldv + lkof;
    const u16* gV1 = gV0 + (size_t)64 * op.ldv;
    const int su0 = (wave * 16) * BK;
    const int su1 = (wave * 16 + 64) * BK;

    f32x4 acc[4][4];
#pragma unroll
    for (int i = 0; i < 4; ++i)
#pragma unroll
        for (int j = 0; j < 4; ++j) acc[i][j] = (f32x4){0.f, 0.f, 0.f, 0.f};

    const int arow = wm + (lane & 15);
    const int brow = wn + (lane & 15);
    // logical chunk kq = lane>>4; physical = kq ^ ((row>>1)&3), row bits 1..2
    // come from lane&15 (adding i*16 / 64 doesn't touch them).
    const int kq = (lane >> 4) ^ ((lane >> 1) & 3);

    // prologue: stage tile 0 into buffer 0
    gld_lds16(gU0, &Us[0][su0]);
    gld_lds16(gU1, &Us[0][su1]);
    gld_lds16(gV0, &Vs[0][su0]);
    gld_lds16(gV1, &Vs[0][su1]);

    int buf = 0;
    for (int kk = 0; kk < op.K; kk += BK) {
        __syncthreads();   // drains vmcnt: buffer `buf` ready; prev reads of buf^1 done
        if (kk + BK < op.K) {
            const int kn = kk + BK;
            gld_lds16(gU0 + kn, &Us[buf ^ 1][su0]);
            gld_lds16(gU1 + kn, &Us[buf ^ 1][su1]);
            gld_lds16(gV0 + kn, &Vs[buf ^ 1][su0]);
            gld_lds16(gV1 + kn, &Vs[buf ^ 1][su1]);
        }
        s16x8 af[4], bfr[4];
#pragma unroll
        for (int i = 0; i < 4; ++i)
            af[i] = ((const s16x8*)Us[buf])[(arow + i * 16) * (BK / 8) + kq];
#pragma unroll
        for (int j = 0; j < 4; ++j)
            bfr[j] = ((const s16x8*)Vs[buf])[(brow + j * 16) * (BK / 8) + kq];
#pragma unroll
        for (int i = 0; i < 4; ++i)
#pragma unroll
            for (int j = 0; j < 4; ++j)
                acc[i][j] = __builtin_amdgcn_mfma_f32_16x16x32_bf16(af[i], bfr[j],
                                                                    acc[i][j], 0, 0, 0);
        buf ^= 1;
    }

    // ---- epilogue ----  C/D layout: col=lane&15, row=(lane>>4)*4+r
    const int ldo = 2048;
    const int ccol = lane & 15;
    const int crow = (lane >> 4) * 4;
#pragma unroll
    for (int i = 0; i < 4; ++i) {
#pragma unroll
        for (int j = 0; j < 4; ++j) {
            const int gr0 = bm * BM + wm + i * 16 + crow;
            const int gc = bn * BN + wn + j * 16 + ccol;
            float v[4];
#pragma unroll
            for (int r = 0; r < 4; ++r) {
                v[r] = acc[i][j][r];
                if (op.Add) v[r] += op.Add[(size_t)(gr0 + r) * ldo + gc];
            }
            if (op.OutB) {
#pragma unroll
                for (int r = 0; r < 4; ++r)
                    op.OutB[(size_t)(gr0 + r) * ldo + gc] = f32_to_bf16(v[r]);
            }
            if (op.OutT) {
                uint2 u;
                u.x = (uint32_t)f32_to_bf16(v[0]) | ((uint32_t)f32_to_bf16(v[1]) << 16);
                u.y = (uint32_t)f32_to_bf16(v[2]) | ((uint32_t)f32_to_bf16(v[3]) << 16);
                *(uint2*)(&op.OutT[(size_t)gc * ldo + gr0]) = u;   // gr0 % 4 == 0
            }
            if (op.OutF) {
#pragma unroll
                for (int r = 0; r < 4; ++r)
                    op.OutF[(size_t)(gr0 + r) * ldo + gc] = v[r];
            }
        }
    }
}

static inline GemmOp mkop(const u16* U, const u16* V, int K, int ldu, int ldv,
                          const float* Add, u16* OutB, u16* OutT, float* OutF) {
    GemmOp o;
    o.U = U; o.V = V; o.Add = Add; o.OutB = OutB; o.OutT = OutT; o.OutF = OutF;
    o.K = K; o.ldu = ldu; o.ldv = ldv;
    return o;
}

extern "C" void kernel_launch(void* const* d_in, const int* in_sizes, int n_in,
                              void* d_out, int out_size, void* d_ws, size_t ws_size,
                              hipStream_t stream) {
    const float* A = (const float*)d_in[0];     // (2048, 2048)
    const float* A_F = (const float*)d_in[1];   // (2048, 2048)
    const float* C = (const float*)d_in[2];     // (512, 2048)
    const float* C_F = (const float*)d_in[3];   // (512, 2048)
    const int n = 2048, p = 512;
    (void)in_sizes; (void)n_in; (void)out_size; (void)ws_size;

    char* ws = (char*)d_ws;
    const size_t MB = 1u << 20;
    // ---- Smith squaring: R <- R + B_i R A_i; B,A <- B^2,A^2. 6 levels = S_64.
    u16* AT   = (u16*)(ws + 0 * MB);    // A^T  bf16  (A_0 transposed form)
    u16* Ab   = (u16*)(ws + 8 * MB);    // A    bf16  (A_0 row form)
    u16* AFT  = (u16*)(ws + 16 * MB);   // B=A_F^T row bf16 (B_0 row form)
    u16* AFb  = (u16*)(ws + 24 * MB);   // A_F  bf16  (B_0 transposed form)
    u16* CFT  = (u16*)(ws + 32 * MB);   // C_F^T bf16 (2048x512)
    u16* CT   = (u16*)(ws + 34 * MB);   // C^T   bf16 (2048x512)
    float* R32 = (float*)(ws + 36 * MB);// running R fp32
    u16* Rb   = (u16*)(ws + 52 * MB);   // running R bf16 row
    u16* XT   = (u16*)(ws + 60 * MB);   // (R*A_i)^T bf16
    u16* Tb1  = (u16*)(ws + 68 * MB);   // ping-pong set 1: B_i row
    u16* TbT1 = (u16*)(ws + 76 * MB);   //                  B_i^T
    u16* Ub1  = (u16*)(ws + 84 * MB);   //                  A_i row
    u16* UbT1 = (u16*)(ws + 92 * MB);   //                  A_i^T

    dim3 tb(32, 8);
    stein_transpose_f32_bf16<<<dim3(64, 64), tb, 0, stream>>>(A, AT, n, n);
    stein_convert_f32_bf16<<<4096, 256, 0, stream>>>(A, Ab, n * n);
    stein_transpose_f32_bf16<<<dim3(64, 64), tb, 0, stream>>>(A_F, AFT, n, n);
    stein_convert_f32_bf16<<<4096, 256, 0, stream>>>(A_F, AFb, n * n);
    stein_transpose_f32_bf16<<<dim3(64, 16), tb, 0, stream>>>(C_F, CFT, p, n);
    stein_transpose_f32_bf16<<<dim3(64, 16), tb, 0, stream>>>(C, CT, p, n);

    dim3 blk(256);
    // R_0 = C_F^T C  (fp32 + bf16 row)
    {
        GemmOp r0 = mkop(CFT, CT, p, p, p, nullptr, Rb, nullptr, R32);
        stein_gemm_nt2<<<dim3(16, 16, 1), blk, 0, stream>>>(r0, r0);
    }

    u16* Tb[2]  = {AFT, Tb1};
    u16* TbT[2] = {AFb, TbT1};
    u16* Ub[2]  = {Ab, Ub1};
    u16* UbT[2] = {AT, UbT1};

    for (int i = 0; i < 6; ++i) {
        const int c = i & 1, nx = c ^ 1;
        // launch1: XT = (R A_i)^T   [+ B_{i+1} = B_i^2 when i<5]
        GemmOp oXT = mkop(Rb, UbT[c], n, n, n, nullptr, nullptr, XT, nullptr);
        if (i < 5) {
            GemmOp oBsq = mkop(Tb[c], TbT[c], n, n, n, nullptr, Tb[nx], TbT[nx], nullptr);
            stein_gemm_nt2<<<dim3(16, 16, 2), blk, 0, stream>>>(oXT, oBsq);
            // launch2: R = B_i X + R  [+ A_{i+1} = A_i^2]
            GemmOp oRup = mkop(Tb[c], XT, n, n, n, R32, Rb, nullptr, R32);
            GemmOp oAsq = mkop(Ub[c], UbT[c], n, n, n, nullptr, Ub[nx], UbT[nx], nullptr);
            stein_gemm_nt2<<<dim3(16, 16, 2), blk, 0, stream>>>(oRup, oAsq);
        } else {
            stein_gemm_nt2<<<dim3(16, 16, 1), blk, 0, stream>>>(oXT, oXT);
            // final: S_64 = B_5 X + R -> fp32 d_out
            GemmOp oFin = mkop(Tb[c], XT, n, n, n, R32, nullptr, nullptr, (float*)d_out);
            stein_gemm_nt2<<<dim3(16, 16, 1), blk, 0, stream>>>(oFin, oFin);
        }
    }
}